// Round 1
// 306.017 us; speedup vs baseline: 1.1328x; 1.1328x over previous
//
#include <hip/hip_runtime.h>

#define D 64
#define N_GRAPHS 128
#define D_OUT 16
#define BCAP 16384   // max edges per 256-node bucket (avg 6400, sigma ~80)
#define TILE 4096    // edges per bin_kernel block

typedef unsigned short u16;
typedef unsigned int u32;
typedef unsigned char u8;

__device__ inline u16 f2bf(float f) {  // round-to-nearest-even
  u32 u = __float_as_uint(f);
  return (u16)((u + 0x7fffu + ((u >> 16) & 1u)) >> 16);
}
__device__ inline float bf2f(u16 b) { return __uint_as_float((u32)b << 16); }

// ===========================================================================
// x (fp32) -> bf16, 4 elems/thread. Side duties (free blocks):
//   block 0:   init CSR cursors; compute cvec = b_rel3@Wlin + b_lin
//   blocks1-8: M1 = Wrel3@Wlin, M2 = Wroot3@Wlin  (layer-3 folded into pool)
// ===========================================================================
__global__ __launch_bounds__(256) void cvt_bf16_kernel(
    const float* __restrict__ in, u16* __restrict__ out, int n4,
    int* __restrict__ cursors, int nbuck,
    const float* __restrict__ Wrel3, const float* __restrict__ Wroot3,
    const float* __restrict__ Wlin, const float* __restrict__ brel3,
    const float* __restrict__ blin,
    float* __restrict__ M1, float* __restrict__ M2, float* __restrict__ cvec) {
  int t = threadIdx.x;
  if (blockIdx.x == 0) {
    if (t < nbuck) cursors[t] = t * BCAP;
    if (t >= 240) {
      int o = t - 240;
      float c = blin[o];
#pragma unroll
      for (int j = 0; j < D; j++) c = fmaf(brel3[j], Wlin[j * D_OUT + o], c);
      cvec[o] = c;
    }
  } else if (blockIdx.x <= 8) {
    int idx = (blockIdx.x - 1) * 256 + t;      // 0..2047
    const float* W = (idx < 1024) ? Wrel3 : Wroot3;
    float* M = (idx < 1024) ? M1 : M2;
    int id = idx & 1023;
    int k = id >> 4, o = id & 15;
    float acc = 0.0f;
#pragma unroll
    for (int j = 0; j < D; j++) acc = fmaf(W[k * D + j], Wlin[j * D_OUT + o], acc);
    M[id] = acc;
  }
  int i = blockIdx.x * 256 + t;
  if (i >= n4) return;
  float4 v = ((const float4*)in)[i];
  ushort4 o4;
  o4.x = f2bf(v.x); o4.y = f2bf(v.y); o4.z = f2bf(v.z); o4.w = f2bf(v.w);
  ((ushort4*)out)[i] = o4;
}

// ===========================================================================
// CSR build: LDS counting sort (scattered work in LDS, contiguous HBM writes).
// Pass 1: bin edges by dst>>8.
// ===========================================================================
__global__ __launch_bounds__(256) void bin_kernel(
    const int* __restrict__ src, const int* __restrict__ dst,
    int* __restrict__ cursors, u32* __restrict__ binned,
    int n_edges, int nbuck) {
  __shared__ u32 ent[TILE];
  __shared__ u8 ebk[TILE];
  __shared__ int hist[256];
  __shared__ int startb[256];
  __shared__ int cur[256];
  __shared__ int gbase[256];
  int t = threadIdx.x;
  hist[t] = 0;
  __syncthreads();

  int base = blockIdx.x * TILE;
  int cnt = n_edges - base;
  if (cnt > TILE) cnt = TILE;

  int mys[16], myd[16];
#pragma unroll
  for (int j = 0; j < 16; j++) {
    int i = base + t + j * 256;
    if (t + j * 256 < cnt) {
      mys[j] = src[i];
      myd[j] = dst[i];
      atomicAdd(&hist[myd[j] >> 8], 1);
    } else {
      myd[j] = -1;
    }
  }
  __syncthreads();
  int myc = hist[t];  // this thread's bucket count (bucket id == t)
  for (int off = 1; off < 256; off <<= 1) {
    int tmp = (t >= off) ? hist[t - off] : 0;
    __syncthreads();
    hist[t] += tmp;
    __syncthreads();
  }
  int excl = hist[t] - myc;
  startb[t] = excl;
  cur[t] = excl;
  __syncthreads();

#pragma unroll
  for (int j = 0; j < 16; j++) {
    if (myd[j] >= 0) {
      int b = myd[j] >> 8;
      int p = atomicAdd(&cur[b], 1);
      ent[p] = ((u32)myd[j] << 16) | (u32)mys[j];
      ebk[p] = (u8)b;
    }
  }
  __syncthreads();

  if (t < nbuck && myc > 0) gbase[t] = atomicAdd(&cursors[t], myc);
  __syncthreads();

#pragma unroll
  for (int j = 0; j < 16; j++) {
    int p = t + j * 256;
    if (p < cnt) {
      int b = ebk[p];
      int gpos = gbase[b] + (p - startb[b]);
      if (gpos < (b + 1) * BCAP) binned[gpos] = ent[p];
    }
  }
}

// Pass 2: one block per bucket. Computes its own edge-base prefix (scan
// kernel folded in), builds the CSR segment in LDS, writes coalesced.
__global__ __launch_bounds__(256) void csr_kernel(
    const u32* __restrict__ binned, const int* __restrict__ cursors,
    u16* __restrict__ csr_src, int* __restrict__ offsets,
    int n_nodes, int nbuck) {
  __shared__ int deg[256];
  __shared__ int cur[256];
  __shared__ int red[256];
  __shared__ u16 lcsr[BCAP];
  int b = blockIdx.x, t = threadIdx.x;
  int cnt = cursors[b] - b * BCAP;
  if (cnt < 0) cnt = 0;
  if (cnt > BCAP) cnt = BCAP;

  // ebase = sum of counts of buckets < b (256-wide reduction, b < 256)
  int c = 0;
  if (t < b) {
    c = cursors[t] - t * BCAP;
    if (c < 0) c = 0;
    if (c > BCAP) c = BCAP;
  }
  red[t] = c;
  __syncthreads();
  for (int off = 128; off > 0; off >>= 1) {
    if (t < off) red[t] += red[t + off];
    __syncthreads();
  }
  int ebase = red[0];

  int nodeBase = b << 8;
  int nn = n_nodes - nodeBase;
  if (nn > 256) nn = 256;

  deg[t] = 0;
  __syncthreads();
  const u32* be = binned + (size_t)b * BCAP;
  for (int i = t; i < cnt; i += 256)
    atomicAdd(&deg[(be[i] >> 16) - nodeBase], 1);
  __syncthreads();
  int myd = deg[t];
  for (int off = 1; off < 256; off <<= 1) {
    int tmp = (t >= off) ? deg[t - off] : 0;
    __syncthreads();
    deg[t] += tmp;
    __syncthreads();
  }
  int loff = deg[t] - myd;  // exclusive
  cur[t] = loff;
  if (t < nn) offsets[nodeBase + t] = ebase + loff;
  if (b == nbuck - 1 && t == 0) offsets[n_nodes] = ebase + cnt;
  __syncthreads();

  for (int i = t; i < cnt; i += 256) {
    u32 e = be[i];
    int ln = (e >> 16) - nodeBase;
    int p = atomicAdd(&cur[ln], 1);
    lcsr[p] = (u16)(e & 0xffffu);
  }
  __syncthreads();
  for (int i = t; i < cnt; i += 256) csr_src[ebase + i] = lcsr[i];
}

// ===========================================================================
// Gather v5: SUBGROUP-PER-NODE. Each 8-lane subgroup owns one node's whole
// edge run (wave = 8 nodes). Waves live ~8x longer -> offsets latency
// amortized, loop reaches pipelined steady state, no cross-subgroup shuffle
// reduce, fully-coalesced 2KB/wave agg store. 2 acc sets keep VGPR < 64.
// ===========================================================================
#define ACC8(a, r)                                                       \
  a[0] += __uint_as_float(r.x << 16); a[1] += __uint_as_float(r.x & 0xffff0000u); \
  a[2] += __uint_as_float(r.y << 16); a[3] += __uint_as_float(r.y & 0xffff0000u); \
  a[4] += __uint_as_float(r.z << 16); a[5] += __uint_as_float(r.z & 0xffff0000u); \
  a[6] += __uint_as_float(r.w << 16); a[7] += __uint_as_float(r.w & 0xffff0000u);

__global__ __launch_bounds__(256) void gather_kernel(
    const u16* __restrict__ h, const int* __restrict__ offsets,
    const u16* __restrict__ csr_src, float* __restrict__ agg, int n_nodes) {
  int wave = blockIdx.x * 4 + (threadIdx.x >> 6);
  int lane = threadIdx.x & 63;
  int sub = lane >> 3;          // node slot within wave
  int fo = (lane & 7) * 8;      // feature offset (bf16 elems)
  int nid = wave * 8 + sub;
  bool valid = nid < n_nodes;
  int node = valid ? nid : 0;
  int start = offsets[node];
  int end = offsets[node + 1];
  if (!valid) end = start;

  float a0[8] = {0, 0, 0, 0, 0, 0, 0, 0};
  float a1[8] = {0, 0, 0, 0, 0, 0, 0, 0};
  int i = start;
  for (; i + 3 < end; i += 4) {
    int s0 = csr_src[i], s1 = csr_src[i + 1], s2 = csr_src[i + 2], s3 = csr_src[i + 3];
    uint4 r0 = *(const uint4*)(h + ((size_t)s0 << 6) + fo);
    uint4 r1 = *(const uint4*)(h + ((size_t)s1 << 6) + fo);
    uint4 r2 = *(const uint4*)(h + ((size_t)s2 << 6) + fo);
    uint4 r3 = *(const uint4*)(h + ((size_t)s3 << 6) + fo);
    ACC8(a0, r0) ACC8(a1, r1) ACC8(a0, r2) ACC8(a1, r3)
  }
  for (; i < end; i++) {
    int s0 = csr_src[i];
    uint4 r0 = *(const uint4*)(h + ((size_t)s0 << 6) + fo);
    ACC8(a0, r0)
  }
#pragma unroll
  for (int k = 0; k < 8; k++) a0[k] += a1[k];
  if (valid) {
    float* ap = agg + ((size_t)node << 6) + fo;
    *(float4*)(ap)     = make_float4(a0[0], a0[1], a0[2], a0[3]);
    *(float4*)(ap + 4) = make_float4(a0[4], a0[5], a0[6], a0[7]);
  }
}

// ===========================================================================
// Dense: out = [relu](agg @ W_rel + b + h @ W_root). Weights in registers,
// readlane broadcast, zero LDS. Only layers 1 and 2 (layer 3 folded away).
// ===========================================================================
__global__ __launch_bounds__(64) void dense_kernel(
    const float* __restrict__ agg, const u16* __restrict__ h,
    const float* __restrict__ Wrel, const float* __restrict__ brel,
    const float* __restrict__ Wroot, u16* __restrict__ out,
    int n_nodes, int do_relu) {
  int lane = threadIdx.x;
  float wrel[D], wroot[D];
#pragma unroll
  for (int k = 0; k < D; k++) {
    wrel[k] = Wrel[k * D + lane];
    wroot[k] = Wroot[k * D + lane];
  }
  float b = brel[lane];

  for (int n = blockIdx.x; n < n_nodes; n += gridDim.x) {
    float va = agg[((size_t)n << 6) + lane];
    float vx = bf2f(h[((size_t)n << 6) + lane]);
    float acc = b;
#pragma unroll
    for (int k = 0; k < D; k++) {
      float sa = __int_as_float(__builtin_amdgcn_readlane(__float_as_int(va), k));
      float sx = __int_as_float(__builtin_amdgcn_readlane(__float_as_int(vx), k));
      acc = fmaf(sa, wrel[k], acc);
      acc = fmaf(sx, wroot[k], acc);
    }
    if (do_relu) acc = fmaxf(acc, 0.0f);
    out[((size_t)n << 6) + lane] = f2bf(acc);
  }
}

// ===========================================================================
// Pool both agg3 (fp32) and h2 (bf16): layer-3 dense is linear + pooling is
// linear, so it commutes to the 128-row side. One block per graph.
// ===========================================================================
__global__ __launch_bounds__(256) void pool_mean2_kernel(
    const float* __restrict__ aggA, const u16* __restrict__ hH,
    const int* __restrict__ batch, float* __restrict__ pooledA,
    float* __restrict__ pooledH, float* __restrict__ pooledCnt, int n_nodes) {
  __shared__ int seg[2];
  __shared__ float redA[256], redH[256];
  int g = blockIdx.x;
  if (threadIdx.x < 2) {
    int target = g + (int)threadIdx.x;
    int lo = 0, hi = n_nodes;
    while (lo < hi) {
      int mid = (lo + hi) >> 1;
      if (batch[mid] < target) lo = mid + 1; else hi = mid;
    }
    seg[threadIdx.x] = lo;
  }
  __syncthreads();
  int start = seg[0], end = seg[1];
  int f = threadIdx.x & 63, sub = threadIdx.x >> 6;
  float aA = 0.0f, aH = 0.0f;
  for (int n = start + sub; n < end; n += 4) {
    aA += aggA[((size_t)n << 6) + f];
    aH += bf2f(hH[((size_t)n << 6) + f]);
  }
  redA[threadIdx.x] = aA;
  redH[threadIdx.x] = aH;
  __syncthreads();
  if (sub == 0) {
    float vA = redA[f] + redA[64 + f] + redA[128 + f] + redA[192 + f];
    float vH = redH[f] + redH[64 + f] + redH[128 + f] + redH[192 + f];
    float cnt = (float)(end - start);
    float inv = 1.0f / fmaxf(cnt, 1.0f);
    pooledA[g * D + f] = vA * inv;
    pooledH[g * D + f] = vH * inv;
    if (f == 0) pooledCnt[g] = cnt;
  }
}

// out[g,o] = pooledA@M1 + pooledH@M2 + cvec  (cvec only if graph non-empty)
__global__ __launch_bounds__(256) void final2_kernel(
    const float* __restrict__ pooledA, const float* __restrict__ pooledH,
    const float* __restrict__ M1, const float* __restrict__ M2,
    const float* __restrict__ cvec, const float* __restrict__ blin,
    const float* __restrict__ pooledCnt, float* __restrict__ out) {
  int idx = blockIdx.x * 256 + threadIdx.x;
  if (idx >= N_GRAPHS * D_OUT) return;
  int g = idx >> 4;
  int o = idx & 15;
  float acc = (pooledCnt[g] > 0.0f) ? cvec[o] : blin[o];
#pragma unroll
  for (int k = 0; k < D; k++) {
    acc = fmaf(pooledA[g * D + k], M1[k * D_OUT + o], acc);
    acc = fmaf(pooledH[g * D + k], M2[k * D_OUT + o], acc);
  }
  out[idx] = acc;
}

extern "C" void kernel_launch(void* const* d_in, const int* in_sizes, int n_in,
                              void* d_out, int out_size, void* d_ws, size_t ws_size,
                              hipStream_t stream) {
  const float* x     = (const float*)d_in[0];
  const int*   ei    = (const int*)d_in[1];
  const int*   batch = (const int*)d_in[3];
  const float* Wrel1 = (const float*)d_in[4];
  const float* brel1 = (const float*)d_in[5];
  const float* Wroot1= (const float*)d_in[6];
  const float* Wrel2 = (const float*)d_in[7];
  const float* brel2 = (const float*)d_in[8];
  const float* Wroot2= (const float*)d_in[9];
  const float* Wrel3 = (const float*)d_in[10];
  const float* brel3 = (const float*)d_in[11];
  const float* Wroot3= (const float*)d_in[12];
  const float* Wlin  = (const float*)d_in[13];
  const float* blin  = (const float*)d_in[14];
  float* out = (float*)d_out;

  const int n_edges = in_sizes[1] / 2;
  const int n_nodes = in_sizes[0] / D;
  const int* src = ei;
  const int* dst = ei + n_edges;
  const int nbuck = (n_nodes + 255) >> 8;  // 196

  // ---- workspace carve-up (binned and agg alias: binned dead after csr) ----
  char* p = (char*)d_ws;
  size_t binned_bytes = (size_t)nbuck * BCAP * sizeof(u32);        // ~12.85MB
  size_t agg_bytes = (size_t)n_nodes * D * sizeof(float);          // 12.8MB
  u32* binned  = (u32*)p;
  float* agg   = (float*)p;
  p += (binned_bytes > agg_bytes ? binned_bytes : agg_bytes);
  float* pooledA = (float*)p; p += (size_t)N_GRAPHS * D * sizeof(float);
  float* pooledH = (float*)p; p += (size_t)N_GRAPHS * D * sizeof(float);
  float* pooledCnt = (float*)p; p += (size_t)N_GRAPHS * sizeof(float);
  float* M1     = (float*)p; p += (size_t)D * D_OUT * sizeof(float);
  float* M2     = (float*)p; p += (size_t)D * D_OUT * sizeof(float);
  float* cvec   = (float*)p; p += 16 * sizeof(float);
  int* cursors  = (int*)p;   p += 256 * sizeof(int);
  int* offsets  = (int*)p;   p += (size_t)(n_nodes + 4) * sizeof(int);
  u16* hX       = (u16*)p;   p += (size_t)n_nodes * D * sizeof(u16);
  u16* h1       = (u16*)p;   p += (size_t)n_nodes * D * sizeof(u16);
  u16* h2       = (u16*)p;   p += (size_t)n_nodes * D * sizeof(u16);
  u16* csr_src  = (u16*)p;   p += (size_t)n_edges * sizeof(u16);

  const int bin_blocks = (n_edges + TILE - 1) / TILE;
  const int gath_blocks = (n_nodes + 31) / 32;   // 8 nodes/wave, 4 waves/block
  const int dense_blocks = 3072;
  const int cvt_n4 = n_nodes * D / 4;

  // ---- CSR build + x->bf16 (+cursor init, +M1/M2/cvec precompute) ----
  cvt_bf16_kernel<<<(cvt_n4 + 255) / 256, 256, 0, stream>>>(
      x, hX, cvt_n4, cursors, nbuck, Wrel3, Wroot3, Wlin, brel3, blin, M1, M2, cvec);
  bin_kernel<<<bin_blocks, 256, 0, stream>>>(src, dst, cursors, binned, n_edges, nbuck);
  csr_kernel<<<nbuck, 256, 0, stream>>>(binned, cursors, csr_src, offsets, n_nodes, nbuck);

  // ---- layer 1 ----
  gather_kernel<<<gath_blocks, 256, 0, stream>>>(hX, offsets, csr_src, agg, n_nodes);
  dense_kernel<<<dense_blocks, 64, 0, stream>>>(agg, hX, Wrel1, brel1, Wroot1, h1, n_nodes, 1);

  // ---- layer 2 ----
  gather_kernel<<<gath_blocks, 256, 0, stream>>>(h1, offsets, csr_src, agg, n_nodes);
  dense_kernel<<<dense_blocks, 64, 0, stream>>>(agg, h1, Wrel2, brel2, Wroot2, h2, n_nodes, 1);

  // ---- layer 3 gather only (dense3 folded into pooled side) ----
  gather_kernel<<<gath_blocks, 256, 0, stream>>>(h2, offsets, csr_src, agg, n_nodes);

  // ---- pool agg3 + h2, then tiny 128-row dense ----
  pool_mean2_kernel<<<N_GRAPHS, 256, 0, stream>>>(agg, h2, batch, pooledA, pooledH, pooledCnt, n_nodes);
  final2_kernel<<<(N_GRAPHS * D_OUT + 255) / 256, 256, 0, stream>>>(
      pooledA, pooledH, M1, M2, cvec, blin, pooledCnt, out);
}

// Round 2
// 256.173 us; speedup vs baseline: 1.3532x; 1.1946x over previous
//
#include <hip/hip_runtime.h>

#define D 64
#define N_GRAPHS 128
#define D_OUT 16
#define BCAP 16384   // max edges per 256-node bucket (avg 6400, sigma ~80)
#define TILE 4096    // edges per bin_kernel block

typedef unsigned short u16;
typedef unsigned int u32;
typedef unsigned char u8;
typedef __attribute__((ext_vector_type(8))) short bf16x8;
typedef __attribute__((ext_vector_type(4))) float f32x4;

__device__ inline u16 f2bf(float f) {  // round-to-nearest-even
  u32 u = __float_as_uint(f);
  return (u16)((u + 0x7fffu + ((u >> 16) & 1u)) >> 16);
}
__device__ inline float bf2f(u16 b) { return __uint_as_float((u32)b << 16); }

// ===========================================================================
// x (fp32) -> bf16, 4 elems/thread. Side duties (spare blocks):
//   block 0:     init CSR cursors; cvec = b_rel3@Wlin + b_lin
//   blocks 1-8:  M1 = Wrel3@Wlin, M2 = Wroot3@Wlin (layer-3 folded into pool)
//   blocks 9-16: Wrel1/Wroot1/Wrel2/Wroot2 -> bf16 TRANSPOSED (WbT[o][k])
//                for MFMA B-fragments in the fused layer kernels.
// ===========================================================================
__global__ __launch_bounds__(256) void cvt_bf16_kernel(
    const float* __restrict__ in, u16* __restrict__ out, int n4,
    int* __restrict__ cursors, int nbuck,
    const float* __restrict__ Wrel1, const float* __restrict__ Wroot1,
    const float* __restrict__ Wrel2, const float* __restrict__ Wroot2,
    const float* __restrict__ Wrel3, const float* __restrict__ Wroot3,
    const float* __restrict__ Wlin, const float* __restrict__ brel3,
    const float* __restrict__ blin,
    float* __restrict__ M1, float* __restrict__ M2, float* __restrict__ cvec,
    u16* __restrict__ WbT1r, u16* __restrict__ WbT1o,
    u16* __restrict__ WbT2r, u16* __restrict__ WbT2o) {
  int t = threadIdx.x;
  if (blockIdx.x == 0) {
    if (t < nbuck) cursors[t] = t * BCAP;
    if (t >= 240) {
      int o = t - 240;
      float c = blin[o];
#pragma unroll
      for (int j = 0; j < D; j++) c = fmaf(brel3[j], Wlin[j * D_OUT + o], c);
      cvec[o] = c;
    }
  } else if (blockIdx.x <= 8) {
    int idx = (blockIdx.x - 1) * 256 + t;      // 0..2047
    const float* W = (idx < 1024) ? Wrel3 : Wroot3;
    float* M = (idx < 1024) ? M1 : M2;
    int id = idx & 1023;
    int k = id >> 4, o = id & 15;
    float acc = 0.0f;
#pragma unroll
    for (int j = 0; j < D; j++) acc = fmaf(W[k * D + j], Wlin[j * D_OUT + o], acc);
    M[id] = acc;
  } else if (blockIdx.x <= 16) {
    int tid = (blockIdx.x - 9) * 256 + t;      // 0..2047; 512 threads per matrix
    int mat = tid >> 9;
    int r = tid & 511;
    int o = r >> 3;            // output column 0..63
    int k0 = (r & 7) * 8;      // k-chunk of 8
    const float* Wsrc = (mat == 0) ? Wrel1 : (mat == 1) ? Wroot1
                       : (mat == 2) ? Wrel2 : Wroot2;
    u16* Wdst = (mat == 0) ? WbT1r : (mat == 1) ? WbT1o
               : (mat == 2) ? WbT2r : WbT2o;
    u16 tmp[8];
#pragma unroll
    for (int j = 0; j < 8; j++) tmp[j] = f2bf(Wsrc[(k0 + j) * D + o]);
    uint4 pw;
    pw.x = (u32)tmp[0] | ((u32)tmp[1] << 16);
    pw.y = (u32)tmp[2] | ((u32)tmp[3] << 16);
    pw.z = (u32)tmp[4] | ((u32)tmp[5] << 16);
    pw.w = (u32)tmp[6] | ((u32)tmp[7] << 16);
    *(uint4*)&Wdst[o * D + k0] = pw;
  }
  int i = blockIdx.x * 256 + t;
  if (i >= n4) return;
  float4 v = ((const float4*)in)[i];
  ushort4 o4;
  o4.x = f2bf(v.x); o4.y = f2bf(v.y); o4.z = f2bf(v.z); o4.w = f2bf(v.w);
  ((ushort4*)out)[i] = o4;
}

// ===========================================================================
// CSR build: LDS counting sort (scattered work in LDS, contiguous HBM writes).
// Pass 1: bin edges by dst>>8.
// ===========================================================================
__global__ __launch_bounds__(256) void bin_kernel(
    const int* __restrict__ src, const int* __restrict__ dst,
    int* __restrict__ cursors, u32* __restrict__ binned,
    int n_edges, int nbuck) {
  __shared__ u32 ent[TILE];
  __shared__ u8 ebk[TILE];
  __shared__ int hist[256];
  __shared__ int startb[256];
  __shared__ int cur[256];
  __shared__ int gbase[256];
  int t = threadIdx.x;
  hist[t] = 0;
  __syncthreads();

  int base = blockIdx.x * TILE;
  int cnt = n_edges - base;
  if (cnt > TILE) cnt = TILE;

  int mys[16], myd[16];
#pragma unroll
  for (int j = 0; j < 16; j++) {
    int i = base + t + j * 256;
    if (t + j * 256 < cnt) {
      mys[j] = src[i];
      myd[j] = dst[i];
      atomicAdd(&hist[myd[j] >> 8], 1);
    } else {
      myd[j] = -1;
    }
  }
  __syncthreads();
  int myc = hist[t];  // this thread's bucket count (bucket id == t)
  for (int off = 1; off < 256; off <<= 1) {
    int tmp = (t >= off) ? hist[t - off] : 0;
    __syncthreads();
    hist[t] += tmp;
    __syncthreads();
  }
  int excl = hist[t] - myc;
  startb[t] = excl;
  cur[t] = excl;
  __syncthreads();

#pragma unroll
  for (int j = 0; j < 16; j++) {
    if (myd[j] >= 0) {
      int b = myd[j] >> 8;
      int p = atomicAdd(&cur[b], 1);
      ent[p] = ((u32)myd[j] << 16) | (u32)mys[j];
      ebk[p] = (u8)b;
    }
  }
  __syncthreads();

  if (t < nbuck && myc > 0) gbase[t] = atomicAdd(&cursors[t], myc);
  __syncthreads();

#pragma unroll
  for (int j = 0; j < 16; j++) {
    int p = t + j * 256;
    if (p < cnt) {
      int b = ebk[p];
      int gpos = gbase[b] + (p - startb[b]);
      if (gpos < (b + 1) * BCAP) binned[gpos] = ent[p];
    }
  }
}

// Pass 2: one block per bucket. Computes its own edge-base prefix (scan
// folded in), builds the CSR segment in LDS, writes coalesced.
__global__ __launch_bounds__(256) void csr_kernel(
    const u32* __restrict__ binned, const int* __restrict__ cursors,
    u16* __restrict__ csr_src, int* __restrict__ offsets,
    int n_nodes, int nbuck) {
  __shared__ int deg[256];
  __shared__ int cur[256];
  __shared__ int red[256];
  __shared__ u16 lcsr[BCAP];
  int b = blockIdx.x, t = threadIdx.x;
  int cnt = cursors[b] - b * BCAP;
  if (cnt < 0) cnt = 0;
  if (cnt > BCAP) cnt = BCAP;

  // ebase = sum of counts of buckets < b (256-wide reduction, b < 256)
  int c = 0;
  if (t < b) {
    c = cursors[t] - t * BCAP;
    if (c < 0) c = 0;
    if (c > BCAP) c = BCAP;
  }
  red[t] = c;
  __syncthreads();
  for (int off = 128; off > 0; off >>= 1) {
    if (t < off) red[t] += red[t + off];
    __syncthreads();
  }
  int ebase = red[0];

  int nodeBase = b << 8;
  int nn = n_nodes - nodeBase;
  if (nn > 256) nn = 256;

  deg[t] = 0;
  __syncthreads();
  const u32* be = binned + (size_t)b * BCAP;
  for (int i = t; i < cnt; i += 256)
    atomicAdd(&deg[(be[i] >> 16) - nodeBase], 1);
  __syncthreads();
  int myd = deg[t];
  for (int off = 1; off < 256; off <<= 1) {
    int tmp = (t >= off) ? deg[t - off] : 0;
    __syncthreads();
    deg[t] += tmp;
    __syncthreads();
  }
  int loff = deg[t] - myd;  // exclusive
  cur[t] = loff;
  if (t < nn) offsets[nodeBase + t] = ebase + loff;
  if (b == nbuck - 1 && t == 0) offsets[n_nodes] = ebase + cnt;
  __syncthreads();

  for (int i = t; i < cnt; i += 256) {
    u32 e = be[i];
    int ln = (e >> 16) - nodeBase;
    int p = atomicAdd(&cur[ln], 1);
    lcsr[p] = (u16)(e & 0xffffu);
  }
  __syncthreads();
  for (int i = t; i < cnt; i += 256) csr_src[ebase + i] = lcsr[i];
}

#define ACC8(a, r)                                                       \
  a[0] += __uint_as_float(r.x << 16); a[1] += __uint_as_float(r.x & 0xffff0000u); \
  a[2] += __uint_as_float(r.y << 16); a[3] += __uint_as_float(r.y & 0xffff0000u); \
  a[4] += __uint_as_float(r.z << 16); a[5] += __uint_as_float(r.z & 0xffff0000u); \
  a[6] += __uint_as_float(r.w << 16); a[7] += __uint_as_float(r.w & 0xffff0000u);

// ===========================================================================
// Fused layer (layers 1,2): gather (subgroup-per-node, 32 nodes/block) ->
// LDS (bf16, +8-elem row pad) -> 4 waves x 8 mfma_f32_16x16x32_bf16 ->
// bias/relu -> h_out (bf16). Kills the standalone dense kernel AND the
// agg fp32 HBM round-trip.
//   A-frag: lane l holds A[l&15][(l>>4)*8+j]  (16B contiguous ds_read)
//   B-frag: lane l holds B[(l>>4)*8+j][l&15] = WbT[l&15-col][k..] contiguous
//   D-frag: col=lane&15, row=(lane>>4)*4+reg  [m89-verified]
// ===========================================================================
__global__ __launch_bounds__(256) void fused_layer_kernel(
    const u16* __restrict__ h, const int* __restrict__ offsets,
    const u16* __restrict__ csr_src,
    const u16* __restrict__ WbTrel, const u16* __restrict__ WbTroot,
    const float* __restrict__ brel,
    u16* __restrict__ h_out, int n_nodes, int do_relu) {
  __shared__ __align__(16) u16 ldsA[32 * 72];  // agg rows, bf16, pad 8
  __shared__ __align__(16) u16 ldsX[32 * 72];  // own rows, bf16, pad 8
  int w = threadIdx.x >> 6;
  int lane = threadIdx.x & 63;
  int sub = lane >> 3;          // node slot within wave
  int fo = (lane & 7) * 8;      // feature offset (bf16 elems)
  int blockBase = blockIdx.x * 32;
  int nid = blockBase + w * 8 + sub;
  bool valid = nid < n_nodes;
  int node = valid ? nid : 0;
  int start = offsets[node];
  int end = offsets[node + 1];
  if (!valid) end = start;
  int lrow = (w * 8 + sub) * 72;

  // own row (root-term input) -> ldsX
  uint4 xr = make_uint4(0, 0, 0, 0);
  if (valid) xr = *(const uint4*)(h + ((size_t)node << 6) + fo);
  *(uint4*)&ldsX[lrow + fo] = xr;

  // gather neighbors
  float a0[8] = {0, 0, 0, 0, 0, 0, 0, 0};
  float a1[8] = {0, 0, 0, 0, 0, 0, 0, 0};
  int i = start;
  for (; i + 3 < end; i += 4) {
    int s0 = csr_src[i], s1 = csr_src[i + 1], s2 = csr_src[i + 2], s3 = csr_src[i + 3];
    uint4 r0 = *(const uint4*)(h + ((size_t)s0 << 6) + fo);
    uint4 r1 = *(const uint4*)(h + ((size_t)s1 << 6) + fo);
    uint4 r2 = *(const uint4*)(h + ((size_t)s2 << 6) + fo);
    uint4 r3 = *(const uint4*)(h + ((size_t)s3 << 6) + fo);
    ACC8(a0, r0) ACC8(a1, r1) ACC8(a0, r2) ACC8(a1, r3)
  }
  for (; i < end; i++) {
    int s0 = csr_src[i];
    uint4 r0 = *(const uint4*)(h + ((size_t)s0 << 6) + fo);
    ACC8(a0, r0)
  }
#pragma unroll
  for (int k = 0; k < 8; k++) a0[k] += a1[k];

  uint4 pa;
  pa.x = (u32)f2bf(a0[0]) | ((u32)f2bf(a0[1]) << 16);
  pa.y = (u32)f2bf(a0[2]) | ((u32)f2bf(a0[3]) << 16);
  pa.z = (u32)f2bf(a0[4]) | ((u32)f2bf(a0[5]) << 16);
  pa.w = (u32)f2bf(a0[6]) | ((u32)f2bf(a0[7]) << 16);
  *(uint4*)&ldsA[lrow + fo] = pa;
  __syncthreads();

  // ---- MFMA dense phase: OUT[32x64] = A@Wrel + X@Wroot + b ----
  int mt = w & 1;               // m-tile (16 nodes)
  int ntb = (w >> 1) * 2;       // first n-tile of this wave's pair
  int lr = lane & 15, lk = lane >> 4;
  int arow = (mt * 16 + lr) * 72;
  bf16x8 af0 = *(const bf16x8*)&ldsA[arow + lk * 8];        // kstep 0
  bf16x8 af1 = *(const bf16x8*)&ldsA[arow + 32 + lk * 8];   // kstep 1
  bf16x8 xf0 = *(const bf16x8*)&ldsX[arow + lk * 8];
  bf16x8 xf1 = *(const bf16x8*)&ldsX[arow + 32 + lk * 8];
#pragma unroll
  for (int tt = 0; tt < 2; tt++) {
    int nt = ntb + tt;
    int wrow = (nt * 16 + lr) * D + lk * 8;
    bf16x8 br0 = *(const bf16x8*)(WbTrel + wrow);
    bf16x8 br1 = *(const bf16x8*)(WbTrel + wrow + 32);
    bf16x8 bo0 = *(const bf16x8*)(WbTroot + wrow);
    bf16x8 bo1 = *(const bf16x8*)(WbTroot + wrow + 32);
    f32x4 acc = {0.0f, 0.0f, 0.0f, 0.0f};
    acc = __builtin_amdgcn_mfma_f32_16x16x32_bf16(af0, br0, acc, 0, 0, 0);
    acc = __builtin_amdgcn_mfma_f32_16x16x32_bf16(af1, br1, acc, 0, 0, 0);
    acc = __builtin_amdgcn_mfma_f32_16x16x32_bf16(xf0, bo0, acc, 0, 0, 0);
    acc = __builtin_amdgcn_mfma_f32_16x16x32_bf16(xf1, bo1, acc, 0, 0, 0);
    float bias = brel[nt * 16 + lr];
#pragma unroll
    for (int r = 0; r < 4; r++) {
      int onode = blockBase + mt * 16 + lk * 4 + r;
      if (onode < n_nodes) {
        float v = acc[r] + bias;
        if (do_relu) v = fmaxf(v, 0.0f);
        h_out[((size_t)onode << 6) + nt * 16 + lr] = f2bf(v);
      }
    }
  }
}

// ===========================================================================
// Gather v5 (layer 3, no dense): subgroup-per-node, writes agg fp32.
// ===========================================================================
__global__ __launch_bounds__(256) void gather_kernel(
    const u16* __restrict__ h, const int* __restrict__ offsets,
    const u16* __restrict__ csr_src, float* __restrict__ agg, int n_nodes) {
  int wave = blockIdx.x * 4 + (threadIdx.x >> 6);
  int lane = threadIdx.x & 63;
  int sub = lane >> 3;
  int fo = (lane & 7) * 8;
  int nid = wave * 8 + sub;
  bool valid = nid < n_nodes;
  int node = valid ? nid : 0;
  int start = offsets[node];
  int end = offsets[node + 1];
  if (!valid) end = start;

  float a0[8] = {0, 0, 0, 0, 0, 0, 0, 0};
  float a1[8] = {0, 0, 0, 0, 0, 0, 0, 0};
  int i = start;
  for (; i + 3 < end; i += 4) {
    int s0 = csr_src[i], s1 = csr_src[i + 1], s2 = csr_src[i + 2], s3 = csr_src[i + 3];
    uint4 r0 = *(const uint4*)(h + ((size_t)s0 << 6) + fo);
    uint4 r1 = *(const uint4*)(h + ((size_t)s1 << 6) + fo);
    uint4 r2 = *(const uint4*)(h + ((size_t)s2 << 6) + fo);
    uint4 r3 = *(const uint4*)(h + ((size_t)s3 << 6) + fo);
    ACC8(a0, r0) ACC8(a1, r1) ACC8(a0, r2) ACC8(a1, r3)
  }
  for (; i < end; i++) {
    int s0 = csr_src[i];
    uint4 r0 = *(const uint4*)(h + ((size_t)s0 << 6) + fo);
    ACC8(a0, r0)
  }
#pragma unroll
  for (int k = 0; k < 8; k++) a0[k] += a1[k];
  if (valid) {
    float* ap = agg + ((size_t)node << 6) + fo;
    *(float4*)(ap)     = make_float4(a0[0], a0[1], a0[2], a0[3]);
    *(float4*)(ap + 4) = make_float4(a0[4], a0[5], a0[6], a0[7]);
  }
}

// ===========================================================================
// Pool both agg3 (fp32) and h2 (bf16): layer-3 dense is linear + pooling is
// linear, so it commutes to the 128-row side. One block per graph.
// ===========================================================================
__global__ __launch_bounds__(256) void pool_mean2_kernel(
    const float* __restrict__ aggA, const u16* __restrict__ hH,
    const int* __restrict__ batch, float* __restrict__ pooledA,
    float* __restrict__ pooledH, float* __restrict__ pooledCnt, int n_nodes) {
  __shared__ int seg[2];
  __shared__ float redA[256], redH[256];
  int g = blockIdx.x;
  if (threadIdx.x < 2) {
    int target = g + (int)threadIdx.x;
    int lo = 0, hi = n_nodes;
    while (lo < hi) {
      int mid = (lo + hi) >> 1;
      if (batch[mid] < target) lo = mid + 1; else hi = mid;
    }
    seg[threadIdx.x] = lo;
  }
  __syncthreads();
  int start = seg[0], end = seg[1];
  int f = threadIdx.x & 63, sub = threadIdx.x >> 6;
  float aA = 0.0f, aH = 0.0f;
  for (int n = start + sub; n < end; n += 4) {
    aA += aggA[((size_t)n << 6) + f];
    aH += bf2f(hH[((size_t)n << 6) + f]);
  }
  redA[threadIdx.x] = aA;
  redH[threadIdx.x] = aH;
  __syncthreads();
  if (sub == 0) {
    float vA = redA[f] + redA[64 + f] + redA[128 + f] + redA[192 + f];
    float vH = redH[f] + redH[64 + f] + redH[128 + f] + redH[192 + f];
    float cnt = (float)(end - start);
    float inv = 1.0f / fmaxf(cnt, 1.0f);
    pooledA[g * D + f] = vA * inv;
    pooledH[g * D + f] = vH * inv;
    if (f == 0) pooledCnt[g] = cnt;
  }
}

// out[g,o] = pooledA@M1 + pooledH@M2 + cvec  (cvec only if graph non-empty)
__global__ __launch_bounds__(256) void final2_kernel(
    const float* __restrict__ pooledA, const float* __restrict__ pooledH,
    const float* __restrict__ M1, const float* __restrict__ M2,
    const float* __restrict__ cvec, const float* __restrict__ blin,
    const float* __restrict__ pooledCnt, float* __restrict__ out) {
  int idx = blockIdx.x * 256 + threadIdx.x;
  if (idx >= N_GRAPHS * D_OUT) return;
  int g = idx >> 4;
  int o = idx & 15;
  float acc = (pooledCnt[g] > 0.0f) ? cvec[o] : blin[o];
#pragma unroll
  for (int k = 0; k < D; k++) {
    acc = fmaf(pooledA[g * D + k], M1[k * D_OUT + o], acc);
    acc = fmaf(pooledH[g * D + k], M2[k * D_OUT + o], acc);
  }
  out[idx] = acc;
}

extern "C" void kernel_launch(void* const* d_in, const int* in_sizes, int n_in,
                              void* d_out, int out_size, void* d_ws, size_t ws_size,
                              hipStream_t stream) {
  const float* x     = (const float*)d_in[0];
  const int*   ei    = (const int*)d_in[1];
  const int*   batch = (const int*)d_in[3];
  const float* Wrel1 = (const float*)d_in[4];
  const float* brel1 = (const float*)d_in[5];
  const float* Wroot1= (const float*)d_in[6];
  const float* Wrel2 = (const float*)d_in[7];
  const float* brel2 = (const float*)d_in[8];
  const float* Wroot2= (const float*)d_in[9];
  const float* Wrel3 = (const float*)d_in[10];
  const float* brel3 = (const float*)d_in[11];
  const float* Wroot3= (const float*)d_in[12];
  const float* Wlin  = (const float*)d_in[13];
  const float* blin  = (const float*)d_in[14];
  float* out = (float*)d_out;

  const int n_edges = in_sizes[1] / 2;
  const int n_nodes = in_sizes[0] / D;
  const int* src = ei;
  const int* dst = ei + n_edges;
  const int nbuck = (n_nodes + 255) >> 8;  // 196

  // ---- workspace carve-up (binned and agg alias: binned dead after csr) ----
  char* p = (char*)d_ws;
  size_t binned_bytes = (size_t)nbuck * BCAP * sizeof(u32);        // ~12.85MB
  size_t agg_bytes = (size_t)n_nodes * D * sizeof(float);          // 12.8MB
  u32* binned  = (u32*)p;
  float* agg   = (float*)p;
  p += (binned_bytes > agg_bytes ? binned_bytes : agg_bytes);
  float* pooledA = (float*)p; p += (size_t)N_GRAPHS * D * sizeof(float);
  float* pooledH = (float*)p; p += (size_t)N_GRAPHS * D * sizeof(float);
  float* pooledCnt = (float*)p; p += (size_t)N_GRAPHS * sizeof(float);
  float* M1     = (float*)p; p += (size_t)D * D_OUT * sizeof(float);
  float* M2     = (float*)p; p += (size_t)D * D_OUT * sizeof(float);
  float* cvec   = (float*)p; p += 16 * sizeof(float);
  int* cursors  = (int*)p;   p += 256 * sizeof(int);
  int* offsets  = (int*)p;   p += (size_t)(n_nodes + 4) * sizeof(int);
  u16* hX       = (u16*)p;   p += (size_t)n_nodes * D * sizeof(u16);
  u16* h1       = (u16*)p;   p += (size_t)n_nodes * D * sizeof(u16);
  u16* h2       = (u16*)p;   p += (size_t)n_nodes * D * sizeof(u16);
  u16* csr_src  = (u16*)p;   p += (size_t)n_edges * sizeof(u16);
  u16* WbT1r    = (u16*)p;   p += (size_t)D * D * sizeof(u16);
  u16* WbT1o    = (u16*)p;   p += (size_t)D * D * sizeof(u16);
  u16* WbT2r    = (u16*)p;   p += (size_t)D * D * sizeof(u16);
  u16* WbT2o    = (u16*)p;   p += (size_t)D * D * sizeof(u16);

  const int bin_blocks = (n_edges + TILE - 1) / TILE;
  const int fused_blocks = (n_nodes + 31) / 32;  // 32 nodes/block
  const int gath_blocks = (n_nodes + 31) / 32;
  const int cvt_n4 = n_nodes * D / 4;

  // ---- CSR build + x->bf16 (+cursors, M1/M2/cvec, W->bf16^T precompute) ----
  cvt_bf16_kernel<<<(cvt_n4 + 255) / 256, 256, 0, stream>>>(
      x, hX, cvt_n4, cursors, nbuck, Wrel1, Wroot1, Wrel2, Wroot2,
      Wrel3, Wroot3, Wlin, brel3, blin, M1, M2, cvec,
      WbT1r, WbT1o, WbT2r, WbT2o);
  bin_kernel<<<bin_blocks, 256, 0, stream>>>(src, dst, cursors, binned, n_edges, nbuck);
  csr_kernel<<<nbuck, 256, 0, stream>>>(binned, cursors, csr_src, offsets, n_nodes, nbuck);

  // ---- layers 1,2: fused gather + MFMA dense ----
  fused_layer_kernel<<<fused_blocks, 256, 0, stream>>>(
      hX, offsets, csr_src, WbT1r, WbT1o, brel1, h1, n_nodes, 1);
  fused_layer_kernel<<<fused_blocks, 256, 0, stream>>>(
      h1, offsets, csr_src, WbT2r, WbT2o, brel2, h2, n_nodes, 1);

  // ---- layer 3 gather only (dense3 folded into pooled side) ----
  gather_kernel<<<gath_blocks, 256, 0, stream>>>(h2, offsets, csr_src, agg, n_nodes);

  // ---- pool agg3 + h2, then tiny 128-row dense ----
  pool_mean2_kernel<<<N_GRAPHS, 256, 0, stream>>>(agg, h2, batch, pooledA, pooledH, pooledCnt, n_nodes);
  final2_kernel<<<(N_GRAPHS * D_OUT + 255) / 256, 256, 0, stream>>>(
      pooledA, pooledH, M1, M2, cvec, blin, pooledCnt, out);
}